// Round 4
// baseline (515.850 us; speedup 1.0000x reference)
//
#include <hip/hip_runtime.h>

// ---------------------------------------------------------------------------
// MultiheadAttention: T=1024, B=8, E=1024, H=16, HD=64, SCALE=0.125
// R4: k_attn at 3 blocks/CU (LDS 74.7K -> 54.3K: halved Ps, mask moved to
//     global additive-float array). Log2-domain softmax, XCD-local grid.
// ---------------------------------------------------------------------------

typedef __bf16 bf16x8 __attribute__((ext_vector_type(8)));
typedef float f32x4 __attribute__((ext_vector_type(4)));

#define LOG2E 1.4426950408889634f
#define QSCALE 0.18033688011112042f  // 0.125 * LOG2E

// round-to-nearest-even (one-time prep kernels)
static __device__ __forceinline__ unsigned short f2bf_rn(float f) {
  union { float f; unsigned u; } x;
  x.f = f;
  unsigned r = (x.u + 0x7fffu + ((x.u >> 16) & 1u)) >> 16;
  return (unsigned short)r;
}
// round-half-up (hot paths: 2 VALU ops)
static __device__ __forceinline__ unsigned short f2bf(float f) {
  union { float f; unsigned u; } x;
  x.f = f;
  return (unsigned short)((x.u + 0x8000u) >> 16);
}

static __device__ __forceinline__ void async_cp16(const void* g, void* l) {
  __builtin_amdgcn_global_load_lds((__attribute__((address_space(1))) void*)g,
                                   (__attribute__((address_space(3))) void*)l,
                                   16, 0, 0);
}

// ---------------- fp32 -> bf16 convert (query) ----------------
__global__ void k_cvt(const float* __restrict__ src, unsigned short* __restrict__ dst) {
  const int idx = blockIdx.x * 256 + threadIdx.x;
  const float4 f = ((const float4*)src)[idx];
  unsigned lo = (unsigned)f2bf_rn(f.x) | ((unsigned)f2bf_rn(f.y) << 16);
  unsigned hi = (unsigned)f2bf_rn(f.z) | ((unsigned)f2bf_rn(f.w) << 16);
  uint2 v; v.x = lo; v.y = hi;
  *(uint2*)(dst + (size_t)idx * 4) = v;
}

// ---------------- mask -> additive float (0 / -1e30) ----------------
__global__ void k_mask(const int* __restrict__ mask, float* __restrict__ Mfg) {
  const int i = blockIdx.x * 256 + threadIdx.x;  // 8192 total
  Mfg[i] = mask[i] ? -1e30f : 0.f;
}

// ---------------- transpose + convert weights: dst[e][d] = src[d][e] -------
__global__ void k_transw(const float* __restrict__ src, unsigned short* __restrict__ dst) {
  __shared__ float tile[32][33];
  const int bx = blockIdx.x << 5;
  const int by = blockIdx.y << 5;
  const int tx = threadIdx.x, ty = threadIdx.y;
#pragma unroll
  for (int i = 0; i < 32; i += 8)
    tile[ty + i][tx] = src[(size_t)(by + ty + i) * 1024 + bx + tx];
  __syncthreads();
#pragma unroll
  for (int i = 0; i < 32; i += 8)
    dst[(size_t)(bx + ty + i) * 1024 + by + tx] = f2bf_rn(tile[tx][ty + i]);
}

// ---------------- bias pretransform: fragment-layout bf16, log2 domain -----
__global__ __launch_bounds__(256, 2) void k_biasT(const float* __restrict__ bias,
                                                  unsigned short* __restrict__ B2) {
  __shared__ unsigned short tile[128 * 132];
  const int tid = threadIdx.x;
  const int ss = blockIdx.x, tt = blockIdx.y, h = blockIdx.z;
  const float* src = bias + ((long)h * 1024 + tt * 128) * 1024 + ss * 128;
#pragma unroll
  for (int c = 0; c < 16; ++c) {
    int flat = c * 256 + tid;
    int row = flat >> 5, col = (flat & 31) << 2;
    float4 v = *(const float4*)(src + (long)row * 1024 + col);
    unsigned short* t4 = &tile[row * 132 + col];
    t4[0] = f2bf_rn(v.x * LOG2E); t4[1] = f2bf_rn(v.y * LOG2E);
    t4[2] = f2bf_rn(v.z * LOG2E); t4[3] = f2bf_rn(v.w * LOG2E);
  }
  __syncthreads();
  const int wid = tid >> 6, lane = tid & 63, lanelo = lane & 15, quad = lane >> 4;
  unsigned short outv[64];
#pragma unroll
  for (int mi = 0; mi < 2; ++mi)
#pragma unroll
    for (int nj = 0; nj < 8; ++nj)
#pragma unroll
      for (int r = 0; r < 4; ++r)
        outv[mi * 32 + nj * 4 + r] =
            tile[(wid * 32 + mi * 16 + quad * 4 + r) * 132 + nj * 16 + lanelo];
  unsigned short* dst = B2 + ((((long)(h * 8 + tt) * 8 + ss) * 256 + tid) << 6);
#pragma unroll
  for (int i = 0; i < 8; ++i) ((uint4*)dst)[i] = ((const uint4*)outv)[i];
}

// ---------------- 128x128 bf16 GEMM mainloop (m97 structure) ----------------
static __device__ __forceinline__ void gemm_tile_128x128(
    const unsigned short* __restrict__ A, const unsigned short* __restrict__ Bt,
    int K, long m0, long n0,
    unsigned short* As, unsigned short* Bs, f32x4 acc[4][4]) {
  const int tid = threadIdx.x;
  const int wid = tid >> 6;
  const int lane = tid & 63;
  const int lanelo = lane & 15;
  const int quad = lane >> 4;
  const int wm = (wid >> 1) << 6;
  const int wn = (wid & 1) << 6;
  const int srow = tid >> 2;
  const int scol = (tid & 3) << 3;

  for (int k0 = 0; k0 < K; k0 += 32) {
    __syncthreads();
    {
      const unsigned short* ga0 = A + (m0 + srow) * K + k0 + scol;
      const unsigned short* ga1 = A + (m0 + srow + 64) * K + k0 + scol;
      const unsigned short* gb0 = Bt + (n0 + srow) * K + k0 + scol;
      const unsigned short* gb1 = Bt + (n0 + srow + 64) * K + k0 + scol;
      char* la = (char*)As + wid * 1024;
      char* lb = (char*)Bs + wid * 1024;
      async_cp16(ga0, la);
      async_cp16(ga1, la + 4096);
      async_cp16(gb0, lb);
      async_cp16(gb1, lb + 4096);
    }
    __syncthreads();
    bf16x8 a[4], b[4];
#pragma unroll
    for (int i = 0; i < 4; ++i) {
      a[i] = *(const bf16x8*)(As + (wm + i * 16 + lanelo) * 32 + quad * 8);
      b[i] = *(const bf16x8*)(Bs + (wn + i * 16 + lanelo) * 32 + quad * 8);
    }
#pragma unroll
    for (int i = 0; i < 4; ++i)
#pragma unroll
      for (int j = 0; j < 4; ++j)
        acc[i][j] = __builtin_amdgcn_mfma_f32_16x16x32_bf16(a[i], b[j], acc[i][j], 0, 0, 0);
  }
}

// ---------------- QKV GEMM with scatter epilogue ----------------
// Qh/Kh: [bh][t][64] bf16 (Q pre-scaled by 0.125*LOG2E); Vt: [bh][d][1024].
__global__ __launch_bounds__(256, 2) void k_gemm_qkv(
    const unsigned short* __restrict__ A, const unsigned short* __restrict__ Bt,
    unsigned short* __restrict__ Qh, unsigned short* __restrict__ Kh,
    unsigned short* __restrict__ Vt) {
  __shared__ unsigned short smem[9216];  // As(4096) + Bs(4096); V-epilogue reuses [128][72]
  unsigned short* As = smem;
  unsigned short* Bs = smem + 4096;
  f32x4 acc[4][4];
  const f32x4 z4 = {0.f, 0.f, 0.f, 0.f};
#pragma unroll
  for (int i = 0; i < 4; ++i)
#pragma unroll
    for (int j = 0; j < 4; ++j) acc[i][j] = z4;

  const long m0 = (long)blockIdx.y * 128;
  const long n0 = (long)blockIdx.x * 128;
  gemm_tile_128x128(A, Bt, 1024, m0, n0, As, Bs, acc);

  const int tid = threadIdx.x;
  const int wid = tid >> 6;
  const int lane = tid & 63;
  const int lanelo = lane & 15;
  const int quad = lane >> 4;
  const int wm = (wid >> 1) << 6;
  const int wn = (wid & 1) << 6;
  const int which = (int)(blockIdx.x >> 3);  // 0:Q 1:K 2:V

  if (which == 2) {
    // V epilogue: LDS transpose -> 32B-run coalesced stores into Vt[bh][d][1024]
    unsigned short* Vt_s = smem;  // [128][72]
    const long t0g = m0 >> 3;
#pragma unroll
    for (int half = 0; half < 2; ++half) {
      __syncthreads();
      if ((wid & 1) == half) {
#pragma unroll
        for (int mi = 0; mi < 4; ++mi)
#pragma unroll
          for (int nj = 0; nj < 4; ++nj)
#pragma unroll
            for (int r = 0; r < 4; ++r)
              Vt_s[(wm + mi * 16 + quad * 4 + r) * 72 + nj * 16 + lanelo] =
                  f2bf(acc[mi][nj][r]);
      }
      __syncthreads();
      const int h = (((int)(n0 & 1023)) >> 6) + half;
#pragma unroll
      for (int pp = 0; pp < 2; ++pp) {
        int p = tid + pp * 256;
        int b = p >> 6, d = p & 63;
        long off = ((long)(b * 16 + h)) << 16;
        __attribute__((aligned(16))) unsigned short vals[16];
#pragma unroll
        for (int t = 0; t < 16; ++t) vals[t] = Vt_s[(t * 8 + b) * 72 + d];
        uint4* dst = (uint4*)(Vt + off + (long)d * 1024 + t0g);
        dst[0] = ((const uint4*)vals)[0];
        dst[1] = ((const uint4*)vals)[1];
      }
    }
  } else {
#pragma unroll
    for (int mi = 0; mi < 4; ++mi)
#pragma unroll
      for (int nj = 0; nj < 4; ++nj)
#pragma unroll
        for (int r = 0; r < 4; ++r) {
          int m = (int)m0 + wm + mi * 16 + quad * 4 + r;
          int n = (int)n0 + wn + nj * 16 + lanelo;
          float v = acc[mi][nj][r];
          int t = m >> 3, b = m & 7;
          int e = n & 1023, h = e >> 6, d = e & 63;
          long off = ((long)(b * 16 + h)) << 16;
          if (which == 0)
            Qh[off + t * 64 + d] = f2bf(v * QSCALE);
          else
            Kh[off + t * 64 + d] = f2bf(v);
        }
  }
}

// ---------------- flash attention (log2-domain, 3 blocks/CU) ----------------
// grid: (128 bh, 8 t-tiles) — same-bh blocks share flat%8 -> same XCD L2.
__global__ __launch_bounds__(256, 3) void k_attn(
    const unsigned short* __restrict__ Qh, const unsigned short* __restrict__ Kh,
    const unsigned short* __restrict__ Vt, const unsigned short* __restrict__ B2,
    const float* __restrict__ Mfg, unsigned short* __restrict__ A2) {
  __shared__ unsigned short Ks[128 * 72];  // [s_loc][64+8 pad]   18432 B
  __shared__ unsigned short Vs[64 * 136];  // [d][128+8 pad]      17408 B
  __shared__ unsigned short Ps[128 * 72];  // [t_loc][64+8 pad]   18432 B

  const int tid = threadIdx.x;
  const int wid = tid >> 6;
  const int lane = tid & 63;
  const int lanelo = lane & 15;
  const int quad = lane >> 4;
  const int bh = blockIdx.x;
  const int b = bh >> 4, h = bh & 15;
  const int tt = blockIdx.y;
  const int t0 = tt * 128;
  const long head = (long)bh << 16;

  // Q fragments straight from global (pre-scaled by 0.125*LOG2E)
  bf16x8 aq[2][2];
#pragma unroll
  for (int mi = 0; mi < 2; ++mi)
#pragma unroll
    for (int ks = 0; ks < 2; ++ks)
      aq[mi][ks] = *(const bf16x8*)(Qh + head +
                                    (long)(t0 + wid * 32 + mi * 16 + lanelo) * 64 +
                                    ks * 32 + quad * 8);

  const f32x4 z4 = {0.f, 0.f, 0.f, 0.f};
  f32x4 Oacc[2][4];
#pragma unroll
  for (int mi = 0; mi < 2; ++mi)
#pragma unroll
    for (int dj = 0; dj < 4; ++dj) Oacc[mi][dj] = z4;
  float mrow[2][4], lrow[2][4];
#pragma unroll
  for (int mi = 0; mi < 2; ++mi)
#pragma unroll
    for (int r = 0; r < 4; ++r) { mrow[mi][r] = -1e30f; lrow[mi][r] = 0.f; }

  const long biasbase = (((long)(h * 8 + tt) * 8) * 256 + tid) << 6;

  for (int s0 = 0; s0 < 1024; s0 += 128) {
    // bias + mask loads: independent, issued before barriers for overlap
    bf16x8 bfr[8];
    {
      const bf16x8* bp8 = (const bf16x8*)(B2 + biasbase + ((long)(s0 >> 7) * 256 << 6));
#pragma unroll
      for (int i = 0; i < 8; ++i) bfr[i] = bp8[i];
    }
    float madd[8];
#pragma unroll
    for (int nj = 0; nj < 8; ++nj)
      madd[nj] = Mfg[(long)b * 1024 + s0 + nj * 16 + lanelo];

    __syncthreads();
    // stage K tile: 128 x 64
#pragma unroll
    for (int c = 0; c < 4; ++c) {
      int flat = c * 2048 + tid * 8;
      int row = flat >> 6, col = flat & 63;
      uint4 v = *(const uint4*)(Kh + head + (long)(s0 + row) * 64 + col);
      *(uint4*)&Ks[row * 72 + col] = v;
    }
    // stage V tile: 64 x 128 from Vt [d][1024]
#pragma unroll
    for (int c = 0; c < 4; ++c) {
      int flat = c * 2048 + tid * 8;
      int row = flat >> 7, col = flat & 127;
      uint4 v = *(const uint4*)(Vt + head + (long)row * 1024 + s0 + col);
      *(uint4*)&Vs[row * 136 + col] = v;
    }
    __syncthreads();

    // S = Q K^T (log2 domain)
    f32x4 S[2][8];
#pragma unroll
    for (int mi = 0; mi < 2; ++mi)
#pragma unroll
      for (int nj = 0; nj < 8; ++nj) S[mi][nj] = z4;
#pragma unroll
    for (int ks = 0; ks < 2; ++ks) {
      bf16x8 bk[8];
#pragma unroll
      for (int nj = 0; nj < 8; ++nj)
        bk[nj] = *(const bf16x8*)(Ks + (nj * 16 + lanelo) * 72 + ks * 32 + quad * 8);
#pragma unroll
      for (int mi = 0; mi < 2; ++mi)
#pragma unroll
        for (int nj = 0; nj < 8; ++nj)
          S[mi][nj] = __builtin_amdgcn_mfma_f32_16x16x32_bf16(aq[mi][ks], bk[nj], S[mi][nj], 0, 0, 0);
    }

    // additive bias + additive mask
#pragma unroll
    for (int mi = 0; mi < 2; ++mi)
#pragma unroll
      for (int nj = 0; nj < 8; ++nj)
#pragma unroll
        for (int r = 0; r < 4; ++r)
          S[mi][nj][r] += (float)bfr[mi * 4 + (nj >> 1)][(nj & 1) * 4 + r] + madd[nj];

    // online softmax per row (log2 domain; masked entries underflow to 0)
#pragma unroll
    for (int mi = 0; mi < 2; ++mi)
#pragma unroll
      for (int r = 0; r < 4; ++r) {
        float mx = -1e30f;
#pragma unroll
        for (int nj = 0; nj < 8; ++nj) mx = fmaxf(mx, S[mi][nj][r]);
        mx = fmaxf(mx, __shfl_xor(mx, 1, 16));
        mx = fmaxf(mx, __shfl_xor(mx, 2, 16));
        mx = fmaxf(mx, __shfl_xor(mx, 4, 16));
        mx = fmaxf(mx, __shfl_xor(mx, 8, 16));
        float mold = mrow[mi][r];
        float mnew = fmaxf(mold, mx);
        float al = exp2f(mold - mnew);
        mrow[mi][r] = mnew;
        float rs = 0.f;
#pragma unroll
        for (int nj = 0; nj < 8; ++nj) {
          float p = exp2f(S[mi][nj][r] - mnew);
          S[mi][nj][r] = p;
          rs += p;
        }
        rs += __shfl_xor(rs, 1, 16);
        rs += __shfl_xor(rs, 2, 16);
        rs += __shfl_xor(rs, 4, 16);
        rs += __shfl_xor(rs, 8, 16);
        lrow[mi][r] = lrow[mi][r] * al + rs;
#pragma unroll
        for (int dj = 0; dj < 4; ++dj) Oacc[mi][dj][r] *= al;
      }

    // O += P V, in two 64-col halves (P rows are wave-private: no barrier)
#pragma unroll
    for (int half = 0; half < 2; ++half) {
#pragma unroll
      for (int mi = 0; mi < 2; ++mi)
#pragma unroll
        for (int njl = 0; njl < 4; ++njl)
#pragma unroll
          for (int r = 0; r < 4; ++r)
            Ps[(wid * 32 + mi * 16 + quad * 4 + r) * 72 + njl * 16 + lanelo] =
                f2bf(S[mi][half * 4 + njl][r]);
#pragma unroll
      for (int ks2 = 0; ks2 < 2; ++ks2) {
        const int ks = half * 2 + ks2;
        bf16x8 ap[2], bv[4];
#pragma unroll
        for (int mi = 0; mi < 2; ++mi)
          ap[mi] = *(const bf16x8*)(Ps + (wid * 32 + mi * 16 + lanelo) * 72 + ks2 * 32 + quad * 8);
#pragma unroll
        for (int dj = 0; dj < 4; ++dj)
          bv[dj] = *(const bf16x8*)(Vs + (dj * 16 + lanelo) * 136 + ks * 32 + quad * 8);
#pragma unroll
        for (int mi = 0; mi < 2; ++mi)
#pragma unroll
          for (int dj = 0; dj < 4; ++dj)
            Oacc[mi][dj] = __builtin_amdgcn_mfma_f32_16x16x32_bf16(ap[mi], bv[dj], Oacc[mi][dj], 0, 0, 0);
      }
    }
  }

  // epilogue: A2[(t*8+b)*1024 + h*64 + d] = O / l
#pragma unroll
  for (int mi = 0; mi < 2; ++mi)
#pragma unroll
    for (int r = 0; r < 4; ++r) {
      float rinv = __builtin_amdgcn_rcpf(lrow[mi][r]);
      int t = t0 + wid * 32 + mi * 16 + quad * 4 + r;
#pragma unroll
      for (int dj = 0; dj < 4; ++dj) {
        int d = dj * 16 + lanelo;
        A2[(long)(t * 8 + b) * 1024 + h * 64 + d] = f2bf(Oacc[mi][dj][r] * rinv);
      }
    }
}

// ---------------- out projection GEMM -> fp32 d_out ----------------
__global__ __launch_bounds__(256, 2) void k_gemm_out(
    const unsigned short* __restrict__ A, const unsigned short* __restrict__ Bt,
    float* __restrict__ out) {
  __shared__ unsigned short As[128 * 32];
  __shared__ unsigned short Bs[128 * 32];
  f32x4 acc[4][4];
  const f32x4 z4 = {0.f, 0.f, 0.f, 0.f};
#pragma unroll
  for (int i = 0; i < 4; ++i)
#pragma unroll
    for (int j = 0; j < 4; ++j) acc[i][j] = z4;

  const long m0 = (long)blockIdx.y * 128;
  const long n0 = (long)blockIdx.x * 128;
  gemm_tile_128x128(A, Bt, 1024, m0, n0, As, Bs, acc);

  const int tid = threadIdx.x;
  const int wid = tid >> 6;
  const int lane = tid & 63;
  const int lanelo = lane & 15;
  const int quad = lane >> 4;
  const int wm = (wid >> 1) << 6;
  const int wn = (wid & 1) << 6;
#pragma unroll
  for (int mi = 0; mi < 4; ++mi)
#pragma unroll
    for (int nj = 0; nj < 4; ++nj)
#pragma unroll
      for (int r = 0; r < 4; ++r) {
        long m = m0 + wm + mi * 16 + quad * 4 + r;
        long n = n0 + wn + nj * 16 + lanelo;
        out[m * 1024 + n] = acc[mi][nj][r];
      }
}

// ---------------- launch ----------------
extern "C" void kernel_launch(void* const* d_in, const int* in_sizes, int n_in,
                              void* d_out, int out_size, void* d_ws, size_t ws_size,
                              hipStream_t stream) {
  const float* query = (const float*)d_in[0];
  const int* mask = (const int*)d_in[1];
  const float* bias = (const float*)d_in[2];
  const float* wq = (const float*)d_in[3];
  const float* wk = (const float*)d_in[4];
  const float* wv = (const float*)d_in[5];
  const float* wo = (const float*)d_in[6];
  float* out = (float*)d_out;

  char* ws = (char*)d_ws;
  const size_t MB = 1024 * 1024;
  unsigned short* Abuf  = (unsigned short*)(ws);             // 16 MB
  unsigned short* WqkvT = (unsigned short*)(ws + 16 * MB);   // 6 MB
  unsigned short* WoT   = (unsigned short*)(ws + 22 * MB);   // 2 MB
  unsigned short* Qh    = (unsigned short*)(ws + 24 * MB);   // 16 MB
  unsigned short* Kh    = (unsigned short*)(ws + 40 * MB);   // 16 MB
  unsigned short* Vt    = (unsigned short*)(ws + 56 * MB);   // 16 MB
  unsigned short* A2    = (unsigned short*)(ws + 72 * MB);   // 16 MB
  unsigned short* B2    = (unsigned short*)(ws + 88 * MB);   // 32 MB
  float*          Mfg   = (float*)(ws + 120 * MB);           // 32 KB

  k_cvt<<<dim3(8192), dim3(256), 0, stream>>>(query, Abuf);
  k_mask<<<dim3(32), dim3(256), 0, stream>>>(mask, Mfg);
  dim3 tb(32, 8);
  k_transw<<<dim3(32, 32), tb, 0, stream>>>(wq, WqkvT);
  k_transw<<<dim3(32, 32), tb, 0, stream>>>(wk, WqkvT + 1024 * 1024);
  k_transw<<<dim3(32, 32), tb, 0, stream>>>(wv, WqkvT + 2 * 1024 * 1024);
  k_transw<<<dim3(32, 32), tb, 0, stream>>>(wo, WoT);
  k_biasT<<<dim3(8, 8, 16), dim3(256), 0, stream>>>(bias, B2);
  k_gemm_qkv<<<dim3(24, 64), dim3(256), 0, stream>>>(Abuf, WqkvT, Qh, Kh, Vt);
  k_attn<<<dim3(128, 8), dim3(256), 0, stream>>>(Qh, Kh, Vt, B2, Mfg, A2);
  k_gemm_out<<<dim3(8, 64), dim3(256), 0, stream>>>(A2, WoT, out);
}

// Round 5
// 390.648 us; speedup vs baseline: 1.3205x; 1.3205x over previous
//
#include <hip/hip_runtime.h>

// ---------------------------------------------------------------------------
// MultiheadAttention: T=1024, B=8, E=1024, H=16, HD=64, SCALE=0.125
// R5: R4's 54.3K-LDS k_attn but with __launch_bounds__(256,2).
//     R4's (256,3) capped VGPR at ~85 -> spilled S to scratch (WRITE_SIZE
//     16KB->364MB, 2.4TB/s spill traffic). With (256,2): VGPR ~120 (<=128 ->
//     4 waves/EU per m69), LDS becomes the limit at 3 blocks/CU.
// ---------------------------------------------------------------------------

typedef __bf16 bf16x8 __attribute__((ext_vector_type(8)));
typedef float f32x4 __attribute__((ext_vector_type(4)));

#define LOG2E 1.4426950408889634f
#define QSCALE 0.18033688011112042f  // 0.125 * LOG2E

// round-to-nearest-even (one-time prep kernels)
static __device__ __forceinline__ unsigned short f2bf_rn(float f) {
  union { float f; unsigned u; } x;
  x.f = f;
  unsigned r = (x.u + 0x7fffu + ((x.u >> 16) & 1u)) >> 16;
  return (unsigned short)r;
}
// round-half-up (hot paths: 2 VALU ops)
static __device__ __forceinline__ unsigned short f2bf(float f) {
  union { float f; unsigned u; } x;
  x.f = f;
  return (unsigned short)((x.u + 0x8000u) >> 16);
}

static __device__ __forceinline__ void async_cp16(const void* g, void* l) {
  __builtin_amdgcn_global_load_lds((__attribute__((address_space(1))) void*)g,
                                   (__attribute__((address_space(3))) void*)l,
                                   16, 0, 0);
}

// ---------------- fp32 -> bf16 convert (query) ----------------
__global__ void k_cvt(const float* __restrict__ src, unsigned short* __restrict__ dst) {
  const int idx = blockIdx.x * 256 + threadIdx.x;
  const float4 f = ((const float4*)src)[idx];
  unsigned lo = (unsigned)f2bf_rn(f.x) | ((unsigned)f2bf_rn(f.y) << 16);
  unsigned hi = (unsigned)f2bf_rn(f.z) | ((unsigned)f2bf_rn(f.w) << 16);
  uint2 v; v.x = lo; v.y = hi;
  *(uint2*)(dst + (size_t)idx * 4) = v;
}

// ---------------- mask -> additive float (0 / -1e30) ----------------
__global__ void k_mask(const int* __restrict__ mask, float* __restrict__ Mfg) {
  const int i = blockIdx.x * 256 + threadIdx.x;  // 8192 total
  Mfg[i] = mask[i] ? -1e30f : 0.f;
}

// ---------------- transpose + convert weights: dst[e][d] = src[d][e] -------
__global__ void k_transw(const float* __restrict__ src, unsigned short* __restrict__ dst) {
  __shared__ float tile[32][33];
  const int bx = blockIdx.x << 5;
  const int by = blockIdx.y << 5;
  const int tx = threadIdx.x, ty = threadIdx.y;
#pragma unroll
  for (int i = 0; i < 32; i += 8)
    tile[ty + i][tx] = src[(size_t)(by + ty + i) * 1024 + bx + tx];
  __syncthreads();
#pragma unroll
  for (int i = 0; i < 32; i += 8)
    dst[(size_t)(bx + ty + i) * 1024 + by + tx] = f2bf_rn(tile[tx][ty + i]);
}

// ---------------- bias pretransform: fragment-layout bf16, log2 domain -----
__global__ __launch_bounds__(256, 2) void k_biasT(const float* __restrict__ bias,
                                                  unsigned short* __restrict__ B2) {
  __shared__ unsigned short tile[128 * 132];
  const int tid = threadIdx.x;
  const int ss = blockIdx.x, tt = blockIdx.y, h = blockIdx.z;
  const float* src = bias + ((long)h * 1024 + tt * 128) * 1024 + ss * 128;
#pragma unroll
  for (int c = 0; c < 16; ++c) {
    int flat = c * 256 + tid;
    int row = flat >> 5, col = (flat & 31) << 2;
    float4 v = *(const float4*)(src + (long)row * 1024 + col);
    unsigned short* t4 = &tile[row * 132 + col];
    t4[0] = f2bf_rn(v.x * LOG2E); t4[1] = f2bf_rn(v.y * LOG2E);
    t4[2] = f2bf_rn(v.z * LOG2E); t4[3] = f2bf_rn(v.w * LOG2E);
  }
  __syncthreads();
  const int wid = tid >> 6, lane = tid & 63, lanelo = lane & 15, quad = lane >> 4;
  unsigned short outv[64];
#pragma unroll
  for (int mi = 0; mi < 2; ++mi)
#pragma unroll
    for (int nj = 0; nj < 8; ++nj)
#pragma unroll
      for (int r = 0; r < 4; ++r)
        outv[mi * 32 + nj * 4 + r] =
            tile[(wid * 32 + mi * 16 + quad * 4 + r) * 132 + nj * 16 + lanelo];
  unsigned short* dst = B2 + ((((long)(h * 8 + tt) * 8 + ss) * 256 + tid) << 6);
#pragma unroll
  for (int i = 0; i < 8; ++i) ((uint4*)dst)[i] = ((const uint4*)outv)[i];
}

// ---------------- 128x128 bf16 GEMM mainloop (m97 structure) ----------------
static __device__ __forceinline__ void gemm_tile_128x128(
    const unsigned short* __restrict__ A, const unsigned short* __restrict__ Bt,
    int K, long m0, long n0,
    unsigned short* As, unsigned short* Bs, f32x4 acc[4][4]) {
  const int tid = threadIdx.x;
  const int wid = tid >> 6;
  const int lane = tid & 63;
  const int lanelo = lane & 15;
  const int quad = lane >> 4;
  const int wm = (wid >> 1) << 6;
  const int wn = (wid & 1) << 6;
  const int srow = tid >> 2;
  const int scol = (tid & 3) << 3;

  for (int k0 = 0; k0 < K; k0 += 32) {
    __syncthreads();
    {
      const unsigned short* ga0 = A + (m0 + srow) * K + k0 + scol;
      const unsigned short* ga1 = A + (m0 + srow + 64) * K + k0 + scol;
      const unsigned short* gb0 = Bt + (n0 + srow) * K + k0 + scol;
      const unsigned short* gb1 = Bt + (n0 + srow + 64) * K + k0 + scol;
      char* la = (char*)As + wid * 1024;
      char* lb = (char*)Bs + wid * 1024;
      async_cp16(ga0, la);
      async_cp16(ga1, la + 4096);
      async_cp16(gb0, lb);
      async_cp16(gb1, lb + 4096);
    }
    __syncthreads();
    bf16x8 a[4], b[4];
#pragma unroll
    for (int i = 0; i < 4; ++i) {
      a[i] = *(const bf16x8*)(As + (wm + i * 16 + lanelo) * 32 + quad * 8);
      b[i] = *(const bf16x8*)(Bs + (wn + i * 16 + lanelo) * 32 + quad * 8);
    }
#pragma unroll
    for (int i = 0; i < 4; ++i)
#pragma unroll
      for (int j = 0; j < 4; ++j)
        acc[i][j] = __builtin_amdgcn_mfma_f32_16x16x32_bf16(a[i], b[j], acc[i][j], 0, 0, 0);
  }
}

// ---------------- QKV GEMM with scatter epilogue ----------------
// Qh/Kh: [bh][t][64] bf16 (Q pre-scaled by 0.125*LOG2E); Vt: [bh][d][1024].
__global__ __launch_bounds__(256, 2) void k_gemm_qkv(
    const unsigned short* __restrict__ A, const unsigned short* __restrict__ Bt,
    unsigned short* __restrict__ Qh, unsigned short* __restrict__ Kh,
    unsigned short* __restrict__ Vt) {
  __shared__ unsigned short smem[9216];  // As(4096) + Bs(4096); V-epilogue reuses [128][72]
  unsigned short* As = smem;
  unsigned short* Bs = smem + 4096;
  f32x4 acc[4][4];
  const f32x4 z4 = {0.f, 0.f, 0.f, 0.f};
#pragma unroll
  for (int i = 0; i < 4; ++i)
#pragma unroll
    for (int j = 0; j < 4; ++j) acc[i][j] = z4;

  const long m0 = (long)blockIdx.y * 128;
  const long n0 = (long)blockIdx.x * 128;
  gemm_tile_128x128(A, Bt, 1024, m0, n0, As, Bs, acc);

  const int tid = threadIdx.x;
  const int wid = tid >> 6;
  const int lane = tid & 63;
  const int lanelo = lane & 15;
  const int quad = lane >> 4;
  const int wm = (wid >> 1) << 6;
  const int wn = (wid & 1) << 6;
  const int which = (int)(blockIdx.x >> 3);  // 0:Q 1:K 2:V

  if (which == 2) {
    // V epilogue: LDS transpose -> 32B-run coalesced stores into Vt[bh][d][1024]
    unsigned short* Vt_s = smem;  // [128][72]
    const long t0g = m0 >> 3;
#pragma unroll
    for (int half = 0; half < 2; ++half) {
      __syncthreads();
      if ((wid & 1) == half) {
#pragma unroll
        for (int mi = 0; mi < 4; ++mi)
#pragma unroll
          for (int nj = 0; nj < 4; ++nj)
#pragma unroll
            for (int r = 0; r < 4; ++r)
              Vt_s[(wm + mi * 16 + quad * 4 + r) * 72 + nj * 16 + lanelo] =
                  f2bf(acc[mi][nj][r]);
      }
      __syncthreads();
      const int h = (((int)(n0 & 1023)) >> 6) + half;
#pragma unroll
      for (int pp = 0; pp < 2; ++pp) {
        int p = tid + pp * 256;
        int b = p >> 6, d = p & 63;
        long off = ((long)(b * 16 + h)) << 16;
        __attribute__((aligned(16))) unsigned short vals[16];
#pragma unroll
        for (int t = 0; t < 16; ++t) vals[t] = Vt_s[(t * 8 + b) * 72 + d];
        uint4* dst = (uint4*)(Vt + off + (long)d * 1024 + t0g);
        dst[0] = ((const uint4*)vals)[0];
        dst[1] = ((const uint4*)vals)[1];
      }
    }
  } else {
#pragma unroll
    for (int mi = 0; mi < 4; ++mi)
#pragma unroll
      for (int nj = 0; nj < 4; ++nj)
#pragma unroll
        for (int r = 0; r < 4; ++r) {
          int m = (int)m0 + wm + mi * 16 + quad * 4 + r;
          int n = (int)n0 + wn + nj * 16 + lanelo;
          float v = acc[mi][nj][r];
          int t = m >> 3, b = m & 7;
          int e = n & 1023, h = e >> 6, d = e & 63;
          long off = ((long)(b * 16 + h)) << 16;
          if (which == 0)
            Qh[off + t * 64 + d] = f2bf(v * QSCALE);
          else
            Kh[off + t * 64 + d] = f2bf(v);
        }
  }
}

// ---------------- flash attention (log2-domain, 3 blocks/CU via LDS) --------
// grid: (128 bh, 8 t-tiles) — same-bh blocks share flat%8 -> same XCD L2.
__global__ __launch_bounds__(256, 2) void k_attn(
    const unsigned short* __restrict__ Qh, const unsigned short* __restrict__ Kh,
    const unsigned short* __restrict__ Vt, const unsigned short* __restrict__ B2,
    const float* __restrict__ Mfg, unsigned short* __restrict__ A2) {
  __shared__ unsigned short Ks[128 * 72];  // [s_loc][64+8 pad]   18432 B
  __shared__ unsigned short Vs[64 * 136];  // [d][128+8 pad]      17408 B
  __shared__ unsigned short Ps[128 * 72];  // [t_loc][64+8 pad]   18432 B

  const int tid = threadIdx.x;
  const int wid = tid >> 6;
  const int lane = tid & 63;
  const int lanelo = lane & 15;
  const int quad = lane >> 4;
  const int bh = blockIdx.x;
  const int b = bh >> 4, h = bh & 15;
  const int tt = blockIdx.y;
  const int t0 = tt * 128;
  const long head = (long)bh << 16;

  // Q fragments straight from global (pre-scaled by 0.125*LOG2E)
  bf16x8 aq[2][2];
#pragma unroll
  for (int mi = 0; mi < 2; ++mi)
#pragma unroll
    for (int ks = 0; ks < 2; ++ks)
      aq[mi][ks] = *(const bf16x8*)(Qh + head +
                                    (long)(t0 + wid * 32 + mi * 16 + lanelo) * 64 +
                                    ks * 32 + quad * 8);

  const f32x4 z4 = {0.f, 0.f, 0.f, 0.f};
  f32x4 Oacc[2][4];
#pragma unroll
  for (int mi = 0; mi < 2; ++mi)
#pragma unroll
    for (int dj = 0; dj < 4; ++dj) Oacc[mi][dj] = z4;
  float mrow[2][4], lrow[2][4];
#pragma unroll
  for (int mi = 0; mi < 2; ++mi)
#pragma unroll
    for (int r = 0; r < 4; ++r) { mrow[mi][r] = -1e30f; lrow[mi][r] = 0.f; }

  const long biasbase = (((long)(h * 8 + tt) * 8) * 256 + tid) << 6;

  for (int s0 = 0; s0 < 1024; s0 += 128) {
    // bias + mask loads: independent, issued before barriers for overlap
    bf16x8 bfr[8];
    {
      const bf16x8* bp8 = (const bf16x8*)(B2 + biasbase + ((long)(s0 >> 7) * 256 << 6));
#pragma unroll
      for (int i = 0; i < 8; ++i) bfr[i] = bp8[i];
    }
    float madd[8];
#pragma unroll
    for (int nj = 0; nj < 8; ++nj)
      madd[nj] = Mfg[(long)b * 1024 + s0 + nj * 16 + lanelo];

    __syncthreads();
    // stage K tile: 128 x 64
#pragma unroll
    for (int c = 0; c < 4; ++c) {
      int flat = c * 2048 + tid * 8;
      int row = flat >> 6, col = flat & 63;
      uint4 v = *(const uint4*)(Kh + head + (long)(s0 + row) * 64 + col);
      *(uint4*)&Ks[row * 72 + col] = v;
    }
    // stage V tile: 64 x 128 from Vt [d][1024]
#pragma unroll
    for (int c = 0; c < 4; ++c) {
      int flat = c * 2048 + tid * 8;
      int row = flat >> 7, col = flat & 127;
      uint4 v = *(const uint4*)(Vt + head + (long)row * 1024 + s0 + col);
      *(uint4*)&Vs[row * 136 + col] = v;
    }
    __syncthreads();

    // S = Q K^T (log2 domain)
    f32x4 S[2][8];
#pragma unroll
    for (int mi = 0; mi < 2; ++mi)
#pragma unroll
      for (int nj = 0; nj < 8; ++nj) S[mi][nj] = z4;
#pragma unroll
    for (int ks = 0; ks < 2; ++ks) {
      bf16x8 bk[8];
#pragma unroll
      for (int nj = 0; nj < 8; ++nj)
        bk[nj] = *(const bf16x8*)(Ks + (nj * 16 + lanelo) * 72 + ks * 32 + quad * 8);
#pragma unroll
      for (int mi = 0; mi < 2; ++mi)
#pragma unroll
        for (int nj = 0; nj < 8; ++nj)
          S[mi][nj] = __builtin_amdgcn_mfma_f32_16x16x32_bf16(aq[mi][ks], bk[nj], S[mi][nj], 0, 0, 0);
    }

    // additive bias + additive mask
#pragma unroll
    for (int mi = 0; mi < 2; ++mi)
#pragma unroll
      for (int nj = 0; nj < 8; ++nj)
#pragma unroll
        for (int r = 0; r < 4; ++r)
          S[mi][nj][r] += (float)bfr[mi * 4 + (nj >> 1)][(nj & 1) * 4 + r] + madd[nj];

    // online softmax per row (log2 domain; masked entries underflow to 0)
#pragma unroll
    for (int mi = 0; mi < 2; ++mi)
#pragma unroll
      for (int r = 0; r < 4; ++r) {
        float mx = -1e30f;
#pragma unroll
        for (int nj = 0; nj < 8; ++nj) mx = fmaxf(mx, S[mi][nj][r]);
        mx = fmaxf(mx, __shfl_xor(mx, 1, 16));
        mx = fmaxf(mx, __shfl_xor(mx, 2, 16));
        mx = fmaxf(mx, __shfl_xor(mx, 4, 16));
        mx = fmaxf(mx, __shfl_xor(mx, 8, 16));
        float mold = mrow[mi][r];
        float mnew = fmaxf(mold, mx);
        float al = exp2f(mold - mnew);
        mrow[mi][r] = mnew;
        float rs = 0.f;
#pragma unroll
        for (int nj = 0; nj < 8; ++nj) {
          float p = exp2f(S[mi][nj][r] - mnew);
          S[mi][nj][r] = p;
          rs += p;
        }
        rs += __shfl_xor(rs, 1, 16);
        rs += __shfl_xor(rs, 2, 16);
        rs += __shfl_xor(rs, 4, 16);
        rs += __shfl_xor(rs, 8, 16);
        lrow[mi][r] = lrow[mi][r] * al + rs;
#pragma unroll
        for (int dj = 0; dj < 4; ++dj) Oacc[mi][dj][r] *= al;
      }

    // O += P V, in two 64-col halves (P rows are wave-private: no barrier)
#pragma unroll
    for (int half = 0; half < 2; ++half) {
#pragma unroll
      for (int mi = 0; mi < 2; ++mi)
#pragma unroll
        for (int njl = 0; njl < 4; ++njl)
#pragma unroll
          for (int r = 0; r < 4; ++r)
            Ps[(wid * 32 + mi * 16 + quad * 4 + r) * 72 + njl * 16 + lanelo] =
                f2bf(S[mi][half * 4 + njl][r]);
#pragma unroll
      for (int ks2 = 0; ks2 < 2; ++ks2) {
        const int ks = half * 2 + ks2;
        bf16x8 ap[2], bv[4];
#pragma unroll
        for (int mi = 0; mi < 2; ++mi)
          ap[mi] = *(const bf16x8*)(Ps + (wid * 32 + mi * 16 + lanelo) * 72 + ks2 * 32 + quad * 8);
#pragma unroll
        for (int dj = 0; dj < 4; ++dj)
          bv[dj] = *(const bf16x8*)(Vs + (dj * 16 + lanelo) * 136 + ks * 32 + quad * 8);
#pragma unroll
        for (int mi = 0; mi < 2; ++mi)
#pragma unroll
          for (int dj = 0; dj < 4; ++dj)
            Oacc[mi][dj] = __builtin_amdgcn_mfma_f32_16x16x32_bf16(ap[mi], bv[dj], Oacc[mi][dj], 0, 0, 0);
      }
    }
  }

  // epilogue: A2[(t*8+b)*1024 + h*64 + d] = O / l
#pragma unroll
  for (int mi = 0; mi < 2; ++mi)
#pragma unroll
    for (int r = 0; r < 4; ++r) {
      float rinv = __builtin_amdgcn_rcpf(lrow[mi][r]);
      int t = t0 + wid * 32 + mi * 16 + quad * 4 + r;
#pragma unroll
      for (int dj = 0; dj < 4; ++dj) {
        int d = dj * 16 + lanelo;
        A2[(long)(t * 8 + b) * 1024 + h * 64 + d] = f2bf(Oacc[mi][dj][r] * rinv);
      }
    }
}

// ---------------- out projection GEMM -> fp32 d_out ----------------
__global__ __launch_bounds__(256, 2) void k_gemm_out(
    const unsigned short* __restrict__ A, const unsigned short* __restrict__ Bt,
    float* __restrict__ out) {
  __shared__ unsigned short As[128 * 32];
  __shared__ unsigned short Bs[128 * 32];
  f32x4 acc[4][4];
  const f32x4 z4 = {0.f, 0.f, 0.f, 0.f};
#pragma unroll
  for (int i = 0; i < 4; ++i)
#pragma unroll
    for (int j = 0; j < 4; ++j) acc[i][j] = z4;

  const long m0 = (long)blockIdx.y * 128;
  const long n0 = (long)blockIdx.x * 128;
  gemm_tile_128x128(A, Bt, 1024, m0, n0, As, Bs, acc);

  const int tid = threadIdx.x;
  const int wid = tid >> 6;
  const int lane = tid & 63;
  const int lanelo = lane & 15;
  const int quad = lane >> 4;
  const int wm = (wid >> 1) << 6;
  const int wn = (wid & 1) << 6;
#pragma unroll
  for (int mi = 0; mi < 4; ++mi)
#pragma unroll
    for (int nj = 0; nj < 4; ++nj)
#pragma unroll
      for (int r = 0; r < 4; ++r) {
        long m = m0 + wm + mi * 16 + quad * 4 + r;
        long n = n0 + wn + nj * 16 + lanelo;
        out[m * 1024 + n] = acc[mi][nj][r];
      }
}

// ---------------- launch ----------------
extern "C" void kernel_launch(void* const* d_in, const int* in_sizes, int n_in,
                              void* d_out, int out_size, void* d_ws, size_t ws_size,
                              hipStream_t stream) {
  const float* query = (const float*)d_in[0];
  const int* mask = (const int*)d_in[1];
  const float* bias = (const float*)d_in[2];
  const float* wq = (const float*)d_in[3];
  const float* wk = (const float*)d_in[4];
  const float* wv = (const float*)d_in[5];
  const float* wo = (const float*)d_in[6];
  float* out = (float*)d_out;

  char* ws = (char*)d_ws;
  const size_t MB = 1024 * 1024;
  unsigned short* Abuf  = (unsigned short*)(ws);             // 16 MB
  unsigned short* WqkvT = (unsigned short*)(ws + 16 * MB);   // 6 MB
  unsigned short* WoT   = (unsigned short*)(ws + 22 * MB);   // 2 MB
  unsigned short* Qh    = (unsigned short*)(ws + 24 * MB);   // 16 MB
  unsigned short* Kh    = (unsigned short*)(ws + 40 * MB);   // 16 MB
  unsigned short* Vt    = (unsigned short*)(ws + 56 * MB);   // 16 MB
  unsigned short* A2    = (unsigned short*)(ws + 72 * MB);   // 16 MB
  unsigned short* B2    = (unsigned short*)(ws + 88 * MB);   // 32 MB
  float*          Mfg   = (float*)(ws + 120 * MB);           // 32 KB

  k_cvt<<<dim3(8192), dim3(256), 0, stream>>>(query, Abuf);
  k_mask<<<dim3(32), dim3(256), 0, stream>>>(mask, Mfg);
  dim3 tb(32, 8);
  k_transw<<<dim3(32, 32), tb, 0, stream>>>(wq, WqkvT);
  k_transw<<<dim3(32, 32), tb, 0, stream>>>(wk, WqkvT + 1024 * 1024);
  k_transw<<<dim3(32, 32), tb, 0, stream>>>(wv, WqkvT + 2 * 1024 * 1024);
  k_transw<<<dim3(32, 32), tb, 0, stream>>>(wo, WoT);
  k_biasT<<<dim3(8, 8, 16), dim3(256), 0, stream>>>(bias, B2);
  k_gemm_qkv<<<dim3(24, 64), dim3(256), 0, stream>>>(Abuf, WqkvT, Qh, Kh, Vt);
  k_attn<<<dim3(128, 8), dim3(256), 0, stream>>>(Qh, Kh, Vt, B2, Mfg, A2);
  k_gemm_out<<<dim3(8, 64), dim3(256), 0, stream>>>(A2, WoT, out);
}